// Round 8
// baseline (669.243 us; speedup 1.0000x reference)
//
#include <hip/hip_runtime.h>

#define N_NODES 50000
#define N_EDGES 800000
#define N_GRAPHS 128
#define D 128
#define NCHUNK 196           // ceil(50000/256)

__device__ __forceinline__ void fma4(float4& a, float w, const float4& h) {
    a.x += w * h.x; a.y += w * h.y; a.z += w * h.z; a.w += w * h.w;
}
__device__ __forceinline__ void add4(float4& a, const float4& h) {
    a.x += h.x; a.y += h.y; a.z += h.z; a.w += h.w;
}

// ---------------------------------------------------------------- CSR build
__global__ __launch_bounds__(256) void k_count(const int* __restrict__ col,
                                               int* __restrict__ counts) {
    int e = blockIdx.x * 256 + threadIdx.x;
    if (e < N_EDGES) atomicAdd(&counts[col[e]], 1);
}

__global__ __launch_bounds__(256) void k_dinv(const int* __restrict__ counts,
                                              float* __restrict__ dinv) {
    int i = blockIdx.x * 256 + threadIdx.x;
    if (i < N_NODES) dinv[i] = rsqrtf((float)(counts[i] + 1)); // +1 self loop
}

__global__ __launch_bounds__(256) void k_chunksum(const int* __restrict__ counts,
                                                  int* __restrict__ partials) {
    __shared__ int s[256];
    int i = blockIdx.x * 256 + threadIdx.x;
    s[threadIdx.x] = (i < N_NODES) ? counts[i] : 0;
    __syncthreads();
    for (int off = 128; off > 0; off >>= 1) {
        if (threadIdx.x < off) s[threadIdx.x] += s[threadIdx.x + off];
        __syncthreads();
    }
    if (threadIdx.x == 0) partials[blockIdx.x] = s[0];
}

__global__ __launch_bounds__(256) void k_scanpart(int* __restrict__ partials, int m) {
    __shared__ int s[256];
    int t = threadIdx.x;
    int orig = (t < m) ? partials[t] : 0;
    s[t] = orig;
    __syncthreads();
    for (int off = 1; off < 256; off <<= 1) {
        int v = (t >= off) ? s[t - off] : 0;
        __syncthreads();
        s[t] += v;
        __syncthreads();
    }
    if (t < m) partials[t] = s[t] - orig;   // exclusive
}

__global__ __launch_bounds__(256) void k_scanchunk(const int* __restrict__ counts,
                                                   const int* __restrict__ partials,
                                                   int* __restrict__ row_ptr,
                                                   int* __restrict__ offs) {
    __shared__ int s[256];
    int i = blockIdx.x * 256 + threadIdx.x;
    int t = threadIdx.x;
    int orig = (i < N_NODES) ? counts[i] : 0;
    s[t] = orig;
    __syncthreads();
    for (int off = 1; off < 256; off <<= 1) {
        int v = (t >= off) ? s[t - off] : 0;
        __syncthreads();
        s[t] += v;
        __syncthreads();
    }
    int ex = s[t] - orig + partials[blockIdx.x];
    if (i < N_NODES) { row_ptr[i] = ex; offs[i] = ex; }
    if (i == N_NODES - 1) row_ptr[N_NODES] = ex + orig;
}

__global__ __launch_bounds__(256) void k_fill(const int* __restrict__ row,
                                              const int* __restrict__ col,
                                              int* __restrict__ offs,
                                              int* __restrict__ esrc) {
    int e = blockIdx.x * 256 + threadIdx.x;
    if (e < N_EDGES) {
        int c = col[e];
        int pos = atomicAdd(&offs[c], 1);
        esrc[pos] = row[e];
    }
}

// ---------------------------------------------------------------- GEMM  y = dinv ⊙ (H @ W)
// Block: 256 threads, 64 rows x 64 cols tile. W half (128x64 = 32 KB) staged once in LDS.
// H read directly from global (addresses uniform across the 16 col-lanes -> coalesced/broadcast).
__global__ __launch_bounds__(256, 5) void k_gemm(const float* __restrict__ H,
                                                 const float* __restrict__ W,
                                                 const float* __restrict__ dinv,
                                                 float* __restrict__ out, int n) {
    __shared__ float Ws[128 * 64];    // 32 KB, k-major within the column half
    const int tid = threadIdx.x;
    const int half = blockIdx.x & 1;           // which 64-column half
    const int row0 = (blockIdx.x >> 1) * 64;   // 64-row tile
    {
        const float4* W4 = (const float4*)W;   // W row stride = 32 float4
        float4* Ws4 = (float4*)Ws;
#pragma unroll
        for (int i = 0; i < 8; ++i) {
            int idx = i * 256 + tid;           // 0..2047
            int k = idx >> 4, c4 = idx & 15;
            Ws4[idx] = W4[k * 32 + half * 16 + c4];
        }
    }
    __syncthreads();
    const int tx = tid & 15;                   // col group: 4 cols
    const int ty = tid >> 4;                   // row group: 4 rows (16 groups = 64 rows)
    const float4* H4 = (const float4*)H;
    const float4* Ws4 = (const float4*)Ws;
    const int r0 = row0 + ty * 4;
    const size_t ra = (size_t)min(r0 + 0, n - 1) * 32;
    const size_t rb = (size_t)min(r0 + 1, n - 1) * 32;
    const size_t rc = (size_t)min(r0 + 2, n - 1) * 32;
    const size_t rd = (size_t)min(r0 + 3, n - 1) * 32;
    float4 acc0 = {0,0,0,0}, acc1 = {0,0,0,0}, acc2 = {0,0,0,0}, acc3 = {0,0,0,0};
#pragma unroll 2
    for (int k4 = 0; k4 < 32; ++k4) {
        float4 a0 = H4[ra + k4];
        float4 a1 = H4[rb + k4];
        float4 a2 = H4[rc + k4];
        float4 a3 = H4[rd + k4];
        float4 b0 = Ws4[(k4 * 4 + 0) * 16 + tx];
        float4 b1 = Ws4[(k4 * 4 + 1) * 16 + tx];
        float4 b2 = Ws4[(k4 * 4 + 2) * 16 + tx];
        float4 b3 = Ws4[(k4 * 4 + 3) * 16 + tx];
        fma4(acc0, a0.x, b0); fma4(acc0, a0.y, b1); fma4(acc0, a0.z, b2); fma4(acc0, a0.w, b3);
        fma4(acc1, a1.x, b0); fma4(acc1, a1.y, b1); fma4(acc1, a1.z, b2); fma4(acc1, a1.w, b3);
        fma4(acc2, a2.x, b0); fma4(acc2, a2.y, b1); fma4(acc2, a2.z, b2); fma4(acc2, a2.w, b3);
        fma4(acc3, a3.x, b0); fma4(acc3, a3.y, b1); fma4(acc3, a3.z, b2); fma4(acc3, a3.w, b3);
    }
    float4* o4 = (float4*)out;
    const int co = half * 16 + tx;
    if (r0 + 0 < n) { float d = dinv[r0 + 0]; acc0.x *= d; acc0.y *= d; acc0.z *= d; acc0.w *= d; o4[(size_t)(r0 + 0) * 32 + co] = acc0; }
    if (r0 + 1 < n) { float d = dinv[r0 + 1]; acc1.x *= d; acc1.y *= d; acc1.z *= d; acc1.w *= d; o4[(size_t)(r0 + 1) * 32 + co] = acc1; }
    if (r0 + 2 < n) { float d = dinv[r0 + 2]; acc2.x *= d; acc2.y *= d; acc2.z *= d; acc2.w *= d; o4[(size_t)(r0 + 2) * 32 + co] = acc2; }
    if (r0 + 3 < n) { float d = dinv[r0 + 3]; acc3.x *= d; acc3.y *= d; acc3.z *= d; acc3.w *= d; o4[(size_t)(r0 + 3) * 32 + co] = acc3; }
}

// ---------------------------------------------------------------- aggregation (feature-chunked, XCD-affine)
// out[c] = dinv[c] * (Σ_{r∈N(c)} y[r] + y[c]) + b,  y = dinv ⊙ HW (from gemm epilogue)
// chunk q = blockIdx.x & 7 -> one 64 B feature slice (16 floats). Round-robin block->XCD
// dispatch makes chunk q resident on XCD q: slice working set = 50000*64 B = 3.2 MB < 4 MiB L2.
// Wave = one (node, chunk): 16 edge-slots x 4 lanes, 64 B gather per edge, butterfly reduce.
template <int RELU>
__global__ __launch_bounds__(256) void k_agg(const float* __restrict__ Y,
                                             const int* __restrict__ rp,
                                             const int* __restrict__ esrc,
                                             const float* __restrict__ dinv,
                                             const float* __restrict__ bias,
                                             float* __restrict__ out) {
    const int q4 = (blockIdx.x & 7) << 2;        // chunk * 4 float4s
    const int c = (blockIdx.x >> 3) * 4 + (threadIdx.x >> 6);  // node (wave-uniform)
    const int lane = threadIdx.x & 63;
    const int slot = lane >> 2;                  // 16 edge slots
    const int fl = lane & 3;                     // float4 index within 64 B slice
    const float4* __restrict__ Y4 = (const float4*)Y;
    const int beg = rp[c], end = rp[c + 1];
    float4 A = {0,0,0,0};
    for (int j = beg + slot; j < end; j += 16)
        add4(A, Y4[(size_t)esrc[j] * 32 + q4 + fl]);
    // butterfly over slot bits (lane bits 2..5)
    A.x += __shfl_xor(A.x, 4);  A.y += __shfl_xor(A.y, 4);  A.z += __shfl_xor(A.z, 4);  A.w += __shfl_xor(A.w, 4);
    A.x += __shfl_xor(A.x, 8);  A.y += __shfl_xor(A.y, 8);  A.z += __shfl_xor(A.z, 8);  A.w += __shfl_xor(A.w, 8);
    A.x += __shfl_xor(A.x, 16); A.y += __shfl_xor(A.y, 16); A.z += __shfl_xor(A.z, 16); A.w += __shfl_xor(A.w, 16);
    A.x += __shfl_xor(A.x, 32); A.y += __shfl_xor(A.y, 32); A.z += __shfl_xor(A.z, 32); A.w += __shfl_xor(A.w, 32);
    if (slot == 0) {
        const float dv = dinv[c];
        float4 yc = Y4[(size_t)c * 32 + q4 + fl];       // self loop
        float4 bb = ((const float4*)bias)[q4 + fl];
        float4 r;
        r.x = dv * (A.x + yc.x) + bb.x;
        r.y = dv * (A.y + yc.y) + bb.y;
        r.z = dv * (A.z + yc.z) + bb.z;
        r.w = dv * (A.w + yc.w) + bb.w;
        if (RELU) {
            r.x = fmaxf(r.x, 0.f); r.y = fmaxf(r.y, 0.f);
            r.z = fmaxf(r.z, 0.f); r.w = fmaxf(r.w, 0.f);
        }
        ((float4*)out)[(size_t)c * 32 + q4 + fl] = r;
    }
}

// ---------------------------------------------------------------- mean pool (sorted batch)
__global__ __launch_bounds__(64) void k_pool(const float* __restrict__ h,
                                             const int* __restrict__ batch,
                                             float* __restrict__ psum,
                                             float* __restrict__ pcnt) {
    const int l = threadIdx.x;                 // 64 lanes, float2 each = 128 dims
    const int start = blockIdx.x * 32;
    if (start >= N_NODES) return;
    const int end = min(start + 32, N_NODES);
    const float2* __restrict__ h2 = (const float2*)h;
    float2 acc = {0.f, 0.f};
    float cnt = 0.f;
    int g = batch[start];
    for (int i = start; i < end; ++i) {
        int gi = batch[i];
        if (gi != g) {
            atomicAdd(&psum[g * D + 2 * l], acc.x);
            atomicAdd(&psum[g * D + 2 * l + 1], acc.y);
            if (l == 0) atomicAdd(&pcnt[g], cnt);
            acc.x = 0.f; acc.y = 0.f; cnt = 0.f; g = gi;
        }
        float2 v = h2[(size_t)i * 64 + l];
        acc.x += v.x; acc.y += v.y; cnt += 1.f;
    }
    atomicAdd(&psum[g * D + 2 * l], acc.x);
    atomicAdd(&psum[g * D + 2 * l + 1], acc.y);
    if (l == 0) atomicAdd(&pcnt[g], cnt);
}

__global__ __launch_bounds__(384) void k_final(const float* __restrict__ psum,
                                               const float* __restrict__ pcnt,
                                               const float* __restrict__ Wlin,
                                               const float* __restrict__ blin,
                                               float* __restrict__ out) {
    int t = threadIdx.x;
    if (t >= N_GRAPHS * 3) return;
    int g = t / 3, o = t % 3;
    float c = fmaxf(pcnt[g], 1.f);
    float acc = 0.f;
#pragma unroll 8
    for (int d = 0; d < D; ++d) acc += psum[g * D + d] * Wlin[d * 3 + o];
    out[t] = acc / c + blin[o];
}

// ---------------------------------------------------------------- launch
extern "C" void kernel_launch(void* const* d_in, const int* in_sizes, int n_in,
                              void* d_out, int out_size, void* d_ws, size_t ws_size,
                              hipStream_t stream) {
    const float* x    = (const float*)d_in[0];
    const int*   row  = (const int*)d_in[1];             // edge_index[0]
    const int*   col  = ((const int*)d_in[1]) + N_EDGES; // edge_index[1]
    const int*   batch = (const int*)d_in[2];
    const float* W1 = (const float*)d_in[3];  const float* b1 = (const float*)d_in[4];
    const float* W2 = (const float*)d_in[5];  const float* b2 = (const float*)d_in[6];
    const float* W3 = (const float*)d_in[7];  const float* b3 = (const float*)d_in[8];
    const float* Wlin = (const float*)d_in[9]; const float* blin = (const float*)d_in[10];
    float* out = (float*)d_out;

    char* w = (char*)d_ws;
    size_t off = 0;
    auto alloc = [&](size_t bytes) { void* p = w + off; off += (bytes + 255) & ~(size_t)255; return p; };
    float* dinv    = (float*)alloc(N_NODES * 4);
    int*   counts  = (int*)alloc(N_NODES * 4);
    int*   row_ptr = (int*)alloc((N_NODES + 1) * 4);
    int*   offs    = (int*)alloc(N_NODES * 4);
    int*   partials= (int*)alloc(256 * 4);
    int*   esrc    = (int*)alloc((size_t)N_EDGES * 4);
    float* bufA    = (float*)alloc((size_t)N_NODES * D * 4);
    float* bufB    = (float*)alloc((size_t)N_NODES * D * 4);
    float* psum    = (float*)alloc(N_GRAPHS * D * 4);
    float* pcnt    = (float*)alloc(N_GRAPHS * 4);

    hipMemsetAsync(counts, 0, N_NODES * 4, stream);
    hipMemsetAsync(psum, 0, N_GRAPHS * D * 4, stream);
    hipMemsetAsync(pcnt, 0, N_GRAPHS * 4, stream);

    const int EB = (N_EDGES + 255) / 256;   // 3125
    k_count<<<EB, 256, 0, stream>>>(col, counts);
    k_dinv<<<NCHUNK, 256, 0, stream>>>(counts, dinv);
    k_chunksum<<<NCHUNK, 256, 0, stream>>>(counts, partials);
    k_scanpart<<<1, 256, 0, stream>>>(partials, NCHUNK);
    k_scanchunk<<<NCHUNK, 256, 0, stream>>>(counts, partials, row_ptr, offs);
    k_fill<<<EB, 256, 0, stream>>>(row, col, offs, esrc);

    const int GB = ((N_NODES + 63) / 64) * 2;  // 782 row-tiles x 2 col-halves = 1564
    const int AB = 8 * (N_NODES / 4);          // 8 chunks x 12500 node-groups = 100000
    const int PB = (N_NODES + 31) / 32;        // 1563 pool blocks

    k_gemm<<<GB, 256, 0, stream>>>(x, W1, dinv, bufA, N_NODES);
    k_agg<1><<<AB, 256, 0, stream>>>(bufA, row_ptr, esrc, dinv, b1, bufB);
    k_gemm<<<GB, 256, 0, stream>>>(bufB, W2, dinv, bufA, N_NODES);
    k_agg<1><<<AB, 256, 0, stream>>>(bufA, row_ptr, esrc, dinv, b2, bufB);
    k_gemm<<<GB, 256, 0, stream>>>(bufB, W3, dinv, bufA, N_NODES);
    k_agg<0><<<AB, 256, 0, stream>>>(bufA, row_ptr, esrc, dinv, b3, bufB);

    k_pool<<<PB, 64, 0, stream>>>(bufB, batch, psum, pcnt);
    k_final<<<1, 384, 0, stream>>>(psum, pcnt, Wlin, blin, out);
}

// Round 9
// 425.019 us; speedup vs baseline: 1.5746x; 1.5746x over previous
//
#include <hip/hip_runtime.h>

#define N_NODES 50000
#define N_EDGES 800000
#define N_GRAPHS 128
#define D 128
#define NCHUNK 196           // ceil(50000/256)

__device__ __forceinline__ void fma4(float4& a, float w, const float4& h) {
    a.x += w * h.x; a.y += w * h.y; a.z += w * h.z; a.w += w * h.w;
}
__device__ __forceinline__ void add4(float4& a, const float4& h) {
    a.x += h.x; a.y += h.y; a.z += h.z; a.w += h.w;
}
// pack 2 fp32 -> packed bf16 pair (round-to-nearest-even)
__device__ __forceinline__ unsigned bf16pair(float x, float y) {
    unsigned xu = __float_as_uint(x), yu = __float_as_uint(y);
    unsigned xr = (xu + 0x7fffu + ((xu >> 16) & 1u)) >> 16;
    unsigned yr = (yu + 0x7fffu + ((yu >> 16) & 1u)) >> 16;
    return xr | (yr << 16);
}
// unpack uint2 (4 bf16) and accumulate into float4
__device__ __forceinline__ void addbf(float4& a, uint2 u) {
    a.x += __uint_as_float(u.x << 16);
    a.y += __uint_as_float(u.x & 0xffff0000u);
    a.z += __uint_as_float(u.y << 16);
    a.w += __uint_as_float(u.y & 0xffff0000u);
}

// ---------------------------------------------------------------- CSR build
__global__ __launch_bounds__(256) void k_count(const int* __restrict__ col,
                                               int* __restrict__ counts) {
    int e = blockIdx.x * 256 + threadIdx.x;
    if (e < N_EDGES) atomicAdd(&counts[col[e]], 1);
}

__global__ __launch_bounds__(256) void k_dinv(const int* __restrict__ counts,
                                              float* __restrict__ dinv) {
    int i = blockIdx.x * 256 + threadIdx.x;
    if (i < N_NODES) dinv[i] = rsqrtf((float)(counts[i] + 1)); // +1 self loop
}

__global__ __launch_bounds__(256) void k_chunksum(const int* __restrict__ counts,
                                                  int* __restrict__ partials) {
    __shared__ int s[256];
    int i = blockIdx.x * 256 + threadIdx.x;
    s[threadIdx.x] = (i < N_NODES) ? counts[i] : 0;
    __syncthreads();
    for (int off = 128; off > 0; off >>= 1) {
        if (threadIdx.x < off) s[threadIdx.x] += s[threadIdx.x + off];
        __syncthreads();
    }
    if (threadIdx.x == 0) partials[blockIdx.x] = s[0];
}

__global__ __launch_bounds__(256) void k_scanpart(int* __restrict__ partials, int m) {
    __shared__ int s[256];
    int t = threadIdx.x;
    int orig = (t < m) ? partials[t] : 0;
    s[t] = orig;
    __syncthreads();
    for (int off = 1; off < 256; off <<= 1) {
        int v = (t >= off) ? s[t - off] : 0;
        __syncthreads();
        s[t] += v;
        __syncthreads();
    }
    if (t < m) partials[t] = s[t] - orig;   // exclusive
}

__global__ __launch_bounds__(256) void k_scanchunk(const int* __restrict__ counts,
                                                   const int* __restrict__ partials,
                                                   int* __restrict__ row_ptr,
                                                   int* __restrict__ offs) {
    __shared__ int s[256];
    int i = blockIdx.x * 256 + threadIdx.x;
    int t = threadIdx.x;
    int orig = (i < N_NODES) ? counts[i] : 0;
    s[t] = orig;
    __syncthreads();
    for (int off = 1; off < 256; off <<= 1) {
        int v = (t >= off) ? s[t - off] : 0;
        __syncthreads();
        s[t] += v;
        __syncthreads();
    }
    int ex = s[t] - orig + partials[blockIdx.x];
    if (i < N_NODES) { row_ptr[i] = ex; offs[i] = ex; }
    if (i == N_NODES - 1) row_ptr[N_NODES] = ex + orig;
}

__global__ __launch_bounds__(256) void k_fill(const int* __restrict__ row,
                                              const int* __restrict__ col,
                                              int* __restrict__ offs,
                                              int* __restrict__ esrc) {
    int e = blockIdx.x * 256 + threadIdx.x;
    if (e < N_EDGES) {
        int c = col[e];
        int pos = atomicAdd(&offs[c], 1);
        esrc[pos] = row[e];
    }
}

// ---------------------------------------------------------------- GEMM  y = dinv ⊙ (H @ W)
// Block: 256 threads, 64 rows x 64 cols tile. W half (128x64 = 32 KB) staged once in LDS.
// Epilogue also packs y to bf16 (ybf) for the gather path.
__global__ __launch_bounds__(256, 5) void k_gemm(const float* __restrict__ H,
                                                 const float* __restrict__ W,
                                                 const float* __restrict__ dinv,
                                                 float* __restrict__ out,
                                                 uint2* __restrict__ ybf, int n) {
    __shared__ float Ws[128 * 64];    // 32 KB, k-major within the column half
    const int tid = threadIdx.x;
    const int half = blockIdx.x & 1;           // which 64-column half
    const int row0 = (blockIdx.x >> 1) * 64;   // 64-row tile
    {
        const float4* W4 = (const float4*)W;   // W row stride = 32 float4
        float4* Ws4 = (float4*)Ws;
#pragma unroll
        for (int i = 0; i < 8; ++i) {
            int idx = i * 256 + tid;           // 0..2047
            int k = idx >> 4, c4 = idx & 15;
            Ws4[idx] = W4[k * 32 + half * 16 + c4];
        }
    }
    __syncthreads();
    const int tx = tid & 15;                   // col group: 4 cols
    const int ty = tid >> 4;                   // row group: 4 rows (16 groups = 64 rows)
    const float4* H4 = (const float4*)H;
    const float4* Ws4 = (const float4*)Ws;
    const int r0 = row0 + ty * 4;
    const size_t ra = (size_t)min(r0 + 0, n - 1) * 32;
    const size_t rb = (size_t)min(r0 + 1, n - 1) * 32;
    const size_t rc = (size_t)min(r0 + 2, n - 1) * 32;
    const size_t rd = (size_t)min(r0 + 3, n - 1) * 32;
    float4 acc0 = {0,0,0,0}, acc1 = {0,0,0,0}, acc2 = {0,0,0,0}, acc3 = {0,0,0,0};
#pragma unroll 2
    for (int k4 = 0; k4 < 32; ++k4) {
        float4 a0 = H4[ra + k4];
        float4 a1 = H4[rb + k4];
        float4 a2 = H4[rc + k4];
        float4 a3 = H4[rd + k4];
        float4 b0 = Ws4[(k4 * 4 + 0) * 16 + tx];
        float4 b1 = Ws4[(k4 * 4 + 1) * 16 + tx];
        float4 b2 = Ws4[(k4 * 4 + 2) * 16 + tx];
        float4 b3 = Ws4[(k4 * 4 + 3) * 16 + tx];
        fma4(acc0, a0.x, b0); fma4(acc0, a0.y, b1); fma4(acc0, a0.z, b2); fma4(acc0, a0.w, b3);
        fma4(acc1, a1.x, b0); fma4(acc1, a1.y, b1); fma4(acc1, a1.z, b2); fma4(acc1, a1.w, b3);
        fma4(acc2, a2.x, b0); fma4(acc2, a2.y, b1); fma4(acc2, a2.z, b2); fma4(acc2, a2.w, b3);
        fma4(acc3, a3.x, b0); fma4(acc3, a3.y, b1); fma4(acc3, a3.z, b2); fma4(acc3, a3.w, b3);
    }
    float4* o4 = (float4*)out;
    const int co = half * 16 + tx;             // float4 col index; also uint2 col index in ybf
#pragma unroll
    for (int r = 0; r < 4; ++r) {
        float4& a = (r == 0) ? acc0 : (r == 1) ? acc1 : (r == 2) ? acc2 : acc3;
        int rr = r0 + r;
        if (rr < n) {
            float d = dinv[rr];
            a.x *= d; a.y *= d; a.z *= d; a.w *= d;
            o4[(size_t)rr * 32 + co] = a;
            uint2 p; p.x = bf16pair(a.x, a.y); p.y = bf16pair(a.z, a.w);
            ybf[(size_t)rr * 32 + co] = p;
        }
    }
}

// ---------------------------------------------------------------- aggregation
// out[c] = dinv[c] * (Σ_{r∈N(c)} y[r] + y[c]) + b.  Neighbor rows gathered in bf16
// (256 B/row), self-loop row read fp32. One wave per node; half-wave per edge-row;
// 4 rows in flight per half with independent fp32 accumulator chains.
template <int RELU>
__global__ __launch_bounds__(256) void k_agg(const uint2* __restrict__ Ybf,
                                             const float* __restrict__ Yself,
                                             const int* __restrict__ rp,
                                             const int* __restrict__ esrc,
                                             const float* __restrict__ dinv,
                                             const float* __restrict__ bias,
                                             float* __restrict__ out) {
    int wid = (blockIdx.x * 256 + threadIdx.x) >> 6;
    int c = __builtin_amdgcn_readfirstlane(wid);
    if (c >= N_NODES) return;
    const int lane = threadIdx.x & 63;
    const int half = lane >> 5;
    const int l = lane & 31;                   // covers cols 4l..4l+3
    const int beg = rp[c], end = rp[c + 1];
    float4 A0 = {0,0,0,0}, A1 = {0,0,0,0}, A2 = {0,0,0,0}, A3 = {0,0,0,0};
    int jj = beg + half;                       // half 0: even slots, half 1: odd slots
    for (; jj + 6 < end; jj += 8) {            // 4 slots per half per iteration
        uint2 u0 = Ybf[(size_t)esrc[jj]     * 32 + l];
        uint2 u1 = Ybf[(size_t)esrc[jj + 2] * 32 + l];
        uint2 u2 = Ybf[(size_t)esrc[jj + 4] * 32 + l];
        uint2 u3 = Ybf[(size_t)esrc[jj + 6] * 32 + l];
        addbf(A0, u0);
        addbf(A1, u1);
        addbf(A2, u2);
        addbf(A3, u3);
    }
    if (jj + 2 < end) {                        // 2 remaining slots for this half
        uint2 u0 = Ybf[(size_t)esrc[jj]     * 32 + l];
        uint2 u1 = Ybf[(size_t)esrc[jj + 2] * 32 + l];
        addbf(A0, u0);
        addbf(A1, u1);
        jj += 4;
    }
    if (jj < end) addbf(A2, Ybf[(size_t)esrc[jj] * 32 + l]);
    if (half == 0) add4(A3, ((const float4*)Yself)[(size_t)c * 32 + l]); // self loop (fp32)
    add4(A0, A1);
    add4(A2, A3);
    add4(A0, A2);
    A0.x += __shfl_xor(A0.x, 32);
    A0.y += __shfl_xor(A0.y, 32);
    A0.z += __shfl_xor(A0.z, 32);
    A0.w += __shfl_xor(A0.w, 32);
    if (half == 0) {
        const float dv = dinv[c];
        float4 bb = ((const float4*)bias)[l];
        float4 r;
        r.x = dv * A0.x + bb.x;
        r.y = dv * A0.y + bb.y;
        r.z = dv * A0.z + bb.z;
        r.w = dv * A0.w + bb.w;
        if (RELU) {
            r.x = fmaxf(r.x, 0.f); r.y = fmaxf(r.y, 0.f);
            r.z = fmaxf(r.z, 0.f); r.w = fmaxf(r.w, 0.f);
        }
        ((float4*)out)[(size_t)c * 32 + l] = r;
    }
}

// ---------------------------------------------------------------- mean pool (sorted batch)
__global__ __launch_bounds__(64) void k_pool(const float* __restrict__ h,
                                             const int* __restrict__ batch,
                                             float* __restrict__ psum,
                                             float* __restrict__ pcnt) {
    const int l = threadIdx.x;                 // 64 lanes, float2 each = 128 dims
    const int start = blockIdx.x * 32;
    if (start >= N_NODES) return;
    const int end = min(start + 32, N_NODES);
    const float2* __restrict__ h2 = (const float2*)h;
    float2 acc = {0.f, 0.f};
    float cnt = 0.f;
    int g = batch[start];
    for (int i = start; i < end; ++i) {
        int gi = batch[i];
        if (gi != g) {
            atomicAdd(&psum[g * D + 2 * l], acc.x);
            atomicAdd(&psum[g * D + 2 * l + 1], acc.y);
            if (l == 0) atomicAdd(&pcnt[g], cnt);
            acc.x = 0.f; acc.y = 0.f; cnt = 0.f; g = gi;
        }
        float2 v = h2[(size_t)i * 64 + l];
        acc.x += v.x; acc.y += v.y; cnt += 1.f;
    }
    atomicAdd(&psum[g * D + 2 * l], acc.x);
    atomicAdd(&psum[g * D + 2 * l + 1], acc.y);
    if (l == 0) atomicAdd(&pcnt[g], cnt);
}

__global__ __launch_bounds__(384) void k_final(const float* __restrict__ psum,
                                               const float* __restrict__ pcnt,
                                               const float* __restrict__ Wlin,
                                               const float* __restrict__ blin,
                                               float* __restrict__ out) {
    int t = threadIdx.x;
    if (t >= N_GRAPHS * 3) return;
    int g = t / 3, o = t % 3;
    float c = fmaxf(pcnt[g], 1.f);
    float acc = 0.f;
#pragma unroll 8
    for (int d = 0; d < D; ++d) acc += psum[g * D + d] * Wlin[d * 3 + o];
    out[t] = acc / c + blin[o];
}

// ---------------------------------------------------------------- launch
extern "C" void kernel_launch(void* const* d_in, const int* in_sizes, int n_in,
                              void* d_out, int out_size, void* d_ws, size_t ws_size,
                              hipStream_t stream) {
    const float* x    = (const float*)d_in[0];
    const int*   row  = (const int*)d_in[1];             // edge_index[0]
    const int*   col  = ((const int*)d_in[1]) + N_EDGES; // edge_index[1]
    const int*   batch = (const int*)d_in[2];
    const float* W1 = (const float*)d_in[3];  const float* b1 = (const float*)d_in[4];
    const float* W2 = (const float*)d_in[5];  const float* b2 = (const float*)d_in[6];
    const float* W3 = (const float*)d_in[7];  const float* b3 = (const float*)d_in[8];
    const float* Wlin = (const float*)d_in[9]; const float* blin = (const float*)d_in[10];
    float* out = (float*)d_out;

    char* w = (char*)d_ws;
    size_t off = 0;
    auto alloc = [&](size_t bytes) { void* p = w + off; off += (bytes + 255) & ~(size_t)255; return p; };
    float* dinv    = (float*)alloc(N_NODES * 4);
    int*   counts  = (int*)alloc(N_NODES * 4);
    int*   row_ptr = (int*)alloc((N_NODES + 1) * 4);
    int*   offs    = (int*)alloc(N_NODES * 4);
    int*   partials= (int*)alloc(256 * 4);
    int*   esrc    = (int*)alloc((size_t)N_EDGES * 4);
    float* bufA    = (float*)alloc((size_t)N_NODES * D * 4);
    float* bufB    = (float*)alloc((size_t)N_NODES * D * 4);
    uint2* ybf     = (uint2*)alloc((size_t)N_NODES * D * 2);   // bf16 shadow of gemm output
    float* psum    = (float*)alloc(N_GRAPHS * D * 4);
    float* pcnt    = (float*)alloc(N_GRAPHS * 4);

    hipMemsetAsync(counts, 0, N_NODES * 4, stream);
    hipMemsetAsync(psum, 0, N_GRAPHS * D * 4, stream);
    hipMemsetAsync(pcnt, 0, N_GRAPHS * 4, stream);

    const int EB = (N_EDGES + 255) / 256;   // 3125
    k_count<<<EB, 256, 0, stream>>>(col, counts);
    k_dinv<<<NCHUNK, 256, 0, stream>>>(counts, dinv);
    k_chunksum<<<NCHUNK, 256, 0, stream>>>(counts, partials);
    k_scanpart<<<1, 256, 0, stream>>>(partials, NCHUNK);
    k_scanchunk<<<NCHUNK, 256, 0, stream>>>(counts, partials, row_ptr, offs);
    k_fill<<<EB, 256, 0, stream>>>(row, col, offs, esrc);

    const int GB = ((N_NODES + 63) / 64) * 2;  // 782 row-tiles x 2 col-halves = 1564
    const int AB = (N_NODES * 64 + 255) / 256; // 12500 agg blocks (1 wave/node)
    const int PB = (N_NODES + 31) / 32;        // 1563 pool blocks

    k_gemm<<<GB, 256, 0, stream>>>(x, W1, dinv, bufA, ybf, N_NODES);
    k_agg<1><<<AB, 256, 0, stream>>>(ybf, bufA, row_ptr, esrc, dinv, b1, bufB);
    k_gemm<<<GB, 256, 0, stream>>>(bufB, W2, dinv, bufA, ybf, N_NODES);
    k_agg<1><<<AB, 256, 0, stream>>>(ybf, bufA, row_ptr, esrc, dinv, b2, bufB);
    k_gemm<<<GB, 256, 0, stream>>>(bufB, W3, dinv, bufA, ybf, N_NODES);
    k_agg<0><<<AB, 256, 0, stream>>>(ybf, bufA, row_ptr, esrc, dinv, b3, bufB);

    k_pool<<<PB, 64, 0, stream>>>(bufB, batch, psum, pcnt);
    k_final<<<1, 384, 0, stream>>>(psum, pcnt, Wlin, blin, out);
}

// Round 12
// 418.012 us; speedup vs baseline: 1.6010x; 1.0168x over previous
//
#include <hip/hip_runtime.h>

#define N_NODES 50000
#define N_EDGES 800000
#define N_GRAPHS 128
#define D 128
#define NCHUNK 196           // ceil(50000/256)

__device__ __forceinline__ void fma4(float4& a, float w, const float4& h) {
    a.x += w * h.x; a.y += w * h.y; a.z += w * h.z; a.w += w * h.w;
}
__device__ __forceinline__ void add4(float4& a, const float4& h) {
    a.x += h.x; a.y += h.y; a.z += h.z; a.w += h.w;
}
// pack 2 fp32 -> packed bf16 pair (round-to-nearest-even)
__device__ __forceinline__ unsigned bf16pair(float x, float y) {
    unsigned xu = __float_as_uint(x), yu = __float_as_uint(y);
    unsigned xr = (xu + 0x7fffu + ((xu >> 16) & 1u)) >> 16;
    unsigned yr = (yu + 0x7fffu + ((yu >> 16) & 1u)) >> 16;
    return xr | (yr << 16);
}
// unpack uint2 (4 bf16) and accumulate into float4
__device__ __forceinline__ void addbf(float4& a, uint2 u) {
    a.x += __uint_as_float(u.x << 16);
    a.y += __uint_as_float(u.x & 0xffff0000u);
    a.z += __uint_as_float(u.y << 16);
    a.w += __uint_as_float(u.y & 0xffff0000u);
}

// ---------------------------------------------------------------- CSR build
// 4 edges per thread, independent atomic chains (ILP test on the scatter wall)
__global__ __launch_bounds__(256) void k_count(const int* __restrict__ col,
                                               int* __restrict__ counts) {
    int e0 = blockIdx.x * 1024 + threadIdx.x;
#pragma unroll
    for (int i = 0; i < 4; ++i) {
        int e = e0 + i * 256;
        if (e < N_EDGES) atomicAdd(&counts[col[e]], 1);
    }
}

__global__ __launch_bounds__(256) void k_dinv(const int* __restrict__ counts,
                                              float* __restrict__ dinv) {
    int i = blockIdx.x * 256 + threadIdx.x;
    if (i < N_NODES) dinv[i] = rsqrtf((float)(counts[i] + 1)); // +1 self loop
}

__global__ __launch_bounds__(256) void k_chunksum(const int* __restrict__ counts,
                                                  int* __restrict__ partials) {
    __shared__ int s[256];
    int i = blockIdx.x * 256 + threadIdx.x;
    s[threadIdx.x] = (i < N_NODES) ? counts[i] : 0;
    __syncthreads();
    for (int off = 128; off > 0; off >>= 1) {
        if (threadIdx.x < off) s[threadIdx.x] += s[threadIdx.x + off];
        __syncthreads();
    }
    if (threadIdx.x == 0) partials[blockIdx.x] = s[0];
}

__global__ __launch_bounds__(256) void k_scanpart(int* __restrict__ partials, int m) {
    __shared__ int s[256];
    int t = threadIdx.x;
    int orig = (t < m) ? partials[t] : 0;
    s[t] = orig;
    __syncthreads();
    for (int off = 1; off < 256; off <<= 1) {
        int v = (t >= off) ? s[t - off] : 0;
        __syncthreads();
        s[t] += v;
        __syncthreads();
    }
    if (t < m) partials[t] = s[t] - orig;   // exclusive
}

__global__ __launch_bounds__(256) void k_scanchunk(const int* __restrict__ counts,
                                                   const int* __restrict__ partials,
                                                   int* __restrict__ row_ptr,
                                                   int* __restrict__ offs) {
    __shared__ int s[256];
    int i = blockIdx.x * 256 + threadIdx.x;
    int t = threadIdx.x;
    int orig = (i < N_NODES) ? counts[i] : 0;
    s[t] = orig;
    __syncthreads();
    for (int off = 1; off < 256; off <<= 1) {
        int v = (t >= off) ? s[t - off] : 0;
        __syncthreads();
        s[t] += v;
        __syncthreads();
    }
    int ex = s[t] - orig + partials[blockIdx.x];
    if (i < N_NODES) { row_ptr[i] = ex; offs[i] = ex; }
    if (i == N_NODES - 1) row_ptr[N_NODES] = ex + orig;
}

__global__ __launch_bounds__(256) void k_fill(const int* __restrict__ row,
                                              const int* __restrict__ col,
                                              int* __restrict__ offs,
                                              int* __restrict__ esrc) {
    int e0 = blockIdx.x * 1024 + threadIdx.x;
    int e1 = e0 + 256, e2 = e0 + 512, e3 = e0 + 768;
    // load sources early (independent of atomics)
    int r0 = (e0 < N_EDGES) ? row[e0] : 0;
    int r1 = (e1 < N_EDGES) ? row[e1] : 0;
    int r2 = (e2 < N_EDGES) ? row[e2] : 0;
    int r3 = (e3 < N_EDGES) ? row[e3] : 0;
    // issue 4 independent atomics
    int p0 = (e0 < N_EDGES) ? atomicAdd(&offs[col[e0]], 1) : 0;
    int p1 = (e1 < N_EDGES) ? atomicAdd(&offs[col[e1]], 1) : 0;
    int p2 = (e2 < N_EDGES) ? atomicAdd(&offs[col[e2]], 1) : 0;
    int p3 = (e3 < N_EDGES) ? atomicAdd(&offs[col[e3]], 1) : 0;
    // 4 independent scattered stores
    if (e0 < N_EDGES) esrc[p0] = r0;
    if (e1 < N_EDGES) esrc[p1] = r1;
    if (e2 < N_EDGES) esrc[p2] = r2;
    if (e3 < N_EDGES) esrc[p3] = r3;
}

// ---------------------------------------------------------------- GEMM  y = dinv ⊙ (H @ W)
// Block: 256 threads, 64 rows x 64 cols tile. W half (128x64 = 32 KB) staged once in LDS.
// Epilogue also packs y to bf16 (ybf) for the gather path.
__global__ __launch_bounds__(256, 5) void k_gemm(const float* __restrict__ H,
                                                 const float* __restrict__ W,
                                                 const float* __restrict__ dinv,
                                                 float* __restrict__ out,
                                                 uint2* __restrict__ ybf, int n) {
    __shared__ float Ws[128 * 64];    // 32 KB, k-major within the column half
    const int tid = threadIdx.x;
    const int half = blockIdx.x & 1;           // which 64-column half
    const int row0 = (blockIdx.x >> 1) * 64;   // 64-row tile
    {
        const float4* W4 = (const float4*)W;   // W row stride = 32 float4
        float4* Ws4 = (float4*)Ws;
#pragma unroll
        for (int i = 0; i < 8; ++i) {
            int idx = i * 256 + tid;           // 0..2047
            int k = idx >> 4, c4 = idx & 15;
            Ws4[idx] = W4[k * 32 + half * 16 + c4];
        }
    }
    __syncthreads();
    const int tx = tid & 15;                   // col group: 4 cols
    const int ty = tid >> 4;                   // row group: 4 rows (16 groups = 64 rows)
    const float4* H4 = (const float4*)H;
    const float4* Ws4 = (const float4*)Ws;
    const int r0 = row0 + ty * 4;
    const size_t ra = (size_t)min(r0 + 0, n - 1) * 32;
    const size_t rb = (size_t)min(r0 + 1, n - 1) * 32;
    const size_t rc = (size_t)min(r0 + 2, n - 1) * 32;
    const size_t rd = (size_t)min(r0 + 3, n - 1) * 32;
    float4 acc0 = {0,0,0,0}, acc1 = {0,0,0,0}, acc2 = {0,0,0,0}, acc3 = {0,0,0,0};
#pragma unroll 2
    for (int k4 = 0; k4 < 32; ++k4) {
        float4 a0 = H4[ra + k4];
        float4 a1 = H4[rb + k4];
        float4 a2 = H4[rc + k4];
        float4 a3 = H4[rd + k4];
        float4 b0 = Ws4[(k4 * 4 + 0) * 16 + tx];
        float4 b1 = Ws4[(k4 * 4 + 1) * 16 + tx];
        float4 b2 = Ws4[(k4 * 4 + 2) * 16 + tx];
        float4 b3 = Ws4[(k4 * 4 + 3) * 16 + tx];
        fma4(acc0, a0.x, b0); fma4(acc0, a0.y, b1); fma4(acc0, a0.z, b2); fma4(acc0, a0.w, b3);
        fma4(acc1, a1.x, b0); fma4(acc1, a1.y, b1); fma4(acc1, a1.z, b2); fma4(acc1, a1.w, b3);
        fma4(acc2, a2.x, b0); fma4(acc2, a2.y, b1); fma4(acc2, a2.z, b2); fma4(acc2, a2.w, b3);
        fma4(acc3, a3.x, b0); fma4(acc3, a3.y, b1); fma4(acc3, a3.z, b2); fma4(acc3, a3.w, b3);
    }
    float4* o4 = (float4*)out;
    const int co = half * 16 + tx;             // float4 col index; also uint2 col index in ybf
#pragma unroll
    for (int r = 0; r < 4; ++r) {
        float4& a = (r == 0) ? acc0 : (r == 1) ? acc1 : (r == 2) ? acc2 : acc3;
        int rr = r0 + r;
        if (rr < n) {
            float d = dinv[rr];
            a.x *= d; a.y *= d; a.z *= d; a.w *= d;
            o4[(size_t)rr * 32 + co] = a;
            uint2 p; p.x = bf16pair(a.x, a.y); p.y = bf16pair(a.z, a.w);
            ybf[(size_t)rr * 32 + co] = p;
        }
    }
}

// ---------------------------------------------------------------- aggregation
// out[c] = dinv[c] * (Σ_{r∈N(c)} y[r] + y[c]) + b.  Neighbor rows gathered in bf16
// (256 B/row), self-loop row read fp32. One wave per node; half-wave per edge-row;
// 4 rows in flight per half with independent fp32 accumulator chains.
template <int RELU>
__global__ __launch_bounds__(256) void k_agg(const uint2* __restrict__ Ybf,
                                             const float* __restrict__ Yself,
                                             const int* __restrict__ rp,
                                             const int* __restrict__ esrc,
                                             const float* __restrict__ dinv,
                                             const float* __restrict__ bias,
                                             float* __restrict__ out) {
    int wid = (blockIdx.x * 256 + threadIdx.x) >> 6;
    int c = __builtin_amdgcn_readfirstlane(wid);
    if (c >= N_NODES) return;
    const int lane = threadIdx.x & 63;
    const int half = lane >> 5;
    const int l = lane & 31;                   // covers cols 4l..4l+3
    const int beg = rp[c], end = rp[c + 1];
    float4 A0 = {0,0,0,0}, A1 = {0,0,0,0}, A2 = {0,0,0,0}, A3 = {0,0,0,0};
    int jj = beg + half;                       // half 0: even slots, half 1: odd slots
    for (; jj + 6 < end; jj += 8) {            // 4 slots per half per iteration
        uint2 u0 = Ybf[(size_t)esrc[jj]     * 32 + l];
        uint2 u1 = Ybf[(size_t)esrc[jj + 2] * 32 + l];
        uint2 u2 = Ybf[(size_t)esrc[jj + 4] * 32 + l];
        uint2 u3 = Ybf[(size_t)esrc[jj + 6] * 32 + l];
        addbf(A0, u0);
        addbf(A1, u1);
        addbf(A2, u2);
        addbf(A3, u3);
    }
    if (jj + 2 < end) {                        // 2 remaining slots for this half
        uint2 u0 = Ybf[(size_t)esrc[jj]     * 32 + l];
        uint2 u1 = Ybf[(size_t)esrc[jj + 2] * 32 + l];
        addbf(A0, u0);
        addbf(A1, u1);
        jj += 4;
    }
    if (jj < end) addbf(A2, Ybf[(size_t)esrc[jj] * 32 + l]);
    if (half == 0) add4(A3, ((const float4*)Yself)[(size_t)c * 32 + l]); // self loop (fp32)
    add4(A0, A1);
    add4(A2, A3);
    add4(A0, A2);
    A0.x += __shfl_xor(A0.x, 32);
    A0.y += __shfl_xor(A0.y, 32);
    A0.z += __shfl_xor(A0.z, 32);
    A0.w += __shfl_xor(A0.w, 32);
    if (half == 0) {
        const float dv = dinv[c];
        float4 bb = ((const float4*)bias)[l];
        float4 r;
        r.x = dv * A0.x + bb.x;
        r.y = dv * A0.y + bb.y;
        r.z = dv * A0.z + bb.z;
        r.w = dv * A0.w + bb.w;
        if (RELU) {
            r.x = fmaxf(r.x, 0.f); r.y = fmaxf(r.y, 0.f);
            r.z = fmaxf(r.z, 0.f); r.w = fmaxf(r.w, 0.f);
        }
        ((float4*)out)[(size_t)c * 32 + l] = r;
    }
}

// ---------------------------------------------------------------- mean pool (sorted batch)
__global__ __launch_bounds__(64) void k_pool(const float* __restrict__ h,
                                             const int* __restrict__ batch,
                                             float* __restrict__ psum,
                                             float* __restrict__ pcnt) {
    const int l = threadIdx.x;                 // 64 lanes, float2 each = 128 dims
    const int start = blockIdx.x * 32;
    if (start >= N_NODES) return;
    const int end = min(start + 32, N_NODES);
    const float2* __restrict__ h2 = (const float2*)h;
    float2 acc = {0.f, 0.f};
    float cnt = 0.f;
    int g = batch[start];
    for (int i = start; i < end; ++i) {
        int gi = batch[i];
        if (gi != g) {
            atomicAdd(&psum[g * D + 2 * l], acc.x);
            atomicAdd(&psum[g * D + 2 * l + 1], acc.y);
            if (l == 0) atomicAdd(&pcnt[g], cnt);
            acc.x = 0.f; acc.y = 0.f; cnt = 0.f; g = gi;
        }
        float2 v = h2[(size_t)i * 64 + l];
        acc.x += v.x; acc.y += v.y; cnt += 1.f;
    }
    atomicAdd(&psum[g * D + 2 * l], acc.x);
    atomicAdd(&psum[g * D + 2 * l + 1], acc.y);
    if (l == 0) atomicAdd(&pcnt[g], cnt);
}

__global__ __launch_bounds__(384) void k_final(const float* __restrict__ psum,
                                               const float* __restrict__ pcnt,
                                               const float* __restrict__ Wlin,
                                               const float* __restrict__ blin,
                                               float* __restrict__ out) {
    int t = threadIdx.x;
    if (t >= N_GRAPHS * 3) return;
    int g = t / 3, o = t % 3;
    float c = fmaxf(pcnt[g], 1.f);
    float acc = 0.f;
#pragma unroll 8
    for (int d = 0; d < D; ++d) acc += psum[g * D + d] * Wlin[d * 3 + o];
    out[t] = acc / c + blin[o];
}

// ---------------------------------------------------------------- launch
extern "C" void kernel_launch(void* const* d_in, const int* in_sizes, int n_in,
                              void* d_out, int out_size, void* d_ws, size_t ws_size,
                              hipStream_t stream) {
    const float* x    = (const float*)d_in[0];
    const int*   row  = (const int*)d_in[1];             // edge_index[0]
    const int*   col  = ((const int*)d_in[1]) + N_EDGES; // edge_index[1]
    const int*   batch = (const int*)d_in[2];
    const float* W1 = (const float*)d_in[3];  const float* b1 = (const float*)d_in[4];
    const float* W2 = (const float*)d_in[5];  const float* b2 = (const float*)d_in[6];
    const float* W3 = (const float*)d_in[7];  const float* b3 = (const float*)d_in[8];
    const float* Wlin = (const float*)d_in[9]; const float* blin = (const float*)d_in[10];
    float* out = (float*)d_out;

    char* w = (char*)d_ws;
    size_t off = 0;
    auto alloc = [&](size_t bytes) { void* p = w + off; off += (bytes + 255) & ~(size_t)255; return p; };
    float* dinv    = (float*)alloc(N_NODES * 4);
    int*   counts  = (int*)alloc(N_NODES * 4);
    int*   row_ptr = (int*)alloc((N_NODES + 1) * 4);
    int*   offs    = (int*)alloc(N_NODES * 4);
    int*   partials= (int*)alloc(256 * 4);
    int*   esrc    = (int*)alloc((size_t)N_EDGES * 4);
    float* bufA    = (float*)alloc((size_t)N_NODES * D * 4);
    float* bufB    = (float*)alloc((size_t)N_NODES * D * 4);
    uint2* ybf     = (uint2*)alloc((size_t)N_NODES * D * 2);   // bf16 shadow of gemm output
    float* psum    = (float*)alloc(N_GRAPHS * D * 4);
    float* pcnt    = (float*)alloc(N_GRAPHS * 4);

    hipMemsetAsync(counts, 0, N_NODES * 4, stream);
    hipMemsetAsync(psum, 0, N_GRAPHS * D * 4, stream);
    hipMemsetAsync(pcnt, 0, N_GRAPHS * 4, stream);

    const int EB4 = (N_EDGES + 1023) / 1024;   // 782 (4 edges/thread)
    k_count<<<EB4, 256, 0, stream>>>(col, counts);
    k_dinv<<<NCHUNK, 256, 0, stream>>>(counts, dinv);
    k_chunksum<<<NCHUNK, 256, 0, stream>>>(counts, partials);
    k_scanpart<<<1, 256, 0, stream>>>(partials, NCHUNK);
    k_scanchunk<<<NCHUNK, 256, 0, stream>>>(counts, partials, row_ptr, offs);
    k_fill<<<EB4, 256, 0, stream>>>(row, col, offs, esrc);

    const int GB = ((N_NODES + 63) / 64) * 2;  // 782 row-tiles x 2 col-halves = 1564
    const int AB = (N_NODES * 64 + 255) / 256; // 12500 agg blocks (1 wave/node)
    const int PB = (N_NODES + 31) / 32;        // 1563 pool blocks

    k_gemm<<<GB, 256, 0, stream>>>(x, W1, dinv, bufA, ybf, N_NODES);
    k_agg<1><<<AB, 256, 0, stream>>>(ybf, bufA, row_ptr, esrc, dinv, b1, bufB);
    k_gemm<<<GB, 256, 0, stream>>>(bufB, W2, dinv, bufA, ybf, N_NODES);
    k_agg<1><<<AB, 256, 0, stream>>>(ybf, bufA, row_ptr, esrc, dinv, b2, bufB);
    k_gemm<<<GB, 256, 0, stream>>>(bufB, W3, dinv, bufA, ybf, N_NODES);
    k_agg<0><<<AB, 256, 0, stream>>>(ybf, bufA, row_ptr, esrc, dinv, b3, bufB);

    k_pool<<<PB, 64, 0, stream>>>(bufB, batch, psum, pcnt);
    k_final<<<1, 384, 0, stream>>>(psum, pcnt, Wlin, blin, out);
}